// Round 6
// baseline (698.353 us; speedup 1.0000x reference)
//
#include <hip/hip_runtime.h>
#include <hip/hip_bf16.h>
#include <math.h>

#define BB   8
#define NTOK 1024
#define DIM  768
#define DFF  3072
#define NP1  1025

typedef __bf16 bf16x8 __attribute__((ext_vector_type(8)));
typedef float  f32x4  __attribute__((ext_vector_type(4)));
typedef float  f32x16 __attribute__((ext_vector_type(16)));

// ---------------- reductions (wave = 64) ----------------
__device__ __forceinline__ float waveMax(float v){
  #pragma unroll
  for (int o = 32; o > 0; o >>= 1) v = fmaxf(v, __shfl_down(v, o, 64));
  return v;
}
__device__ __forceinline__ float waveSum(float v){
  #pragma unroll
  for (int o = 32; o > 0; o >>= 1) v += __shfl_down(v, o, 64);
  return v;
}
__device__ __forceinline__ float blockMax(float v, float* red){
  int lane = threadIdx.x & 63, w = threadIdx.x >> 6;
  v = waveMax(v);
  if (lane == 0) red[w] = v;
  __syncthreads();
  float r = fmaxf(fmaxf(red[0], red[1]), fmaxf(red[2], red[3]));
  __syncthreads();
  return r;
}
__device__ __forceinline__ float blockSum(float v, float* red){
  int lane = threadIdx.x & 63, w = threadIdx.x >> 6;
  v = waveSum(v);
  if (lane == 0) red[w] = v;
  __syncthreads();
  float r = red[0] + red[1] + red[2] + red[3];
  __syncthreads();
  return r;
}

// ---------------- pos softmax ----------------
__global__ __launch_bounds__(256) void pos_kernel(
    const float* __restrict__ coords, const float* __restrict__ pos_emb,
    const float* __restrict__ p_temp, float* __restrict__ pos)
{
  int i = blockIdx.x;
  int tid = threadIdx.x;
  __shared__ float red[4];
  __shared__ float pe[6];
  if (tid < 6) pe[tid] = pos_emb[i*6 + tid];
  __syncthreads();
  float pt = fabsf(p_temp[0]);
  float v[4]; float mx = -INFINITY;
  #pragma unroll
  for (int j = 0; j < 4; j++){
    int jj = tid + j*256;
    const float* c = coords + ((long long)i*NTOK + jj)*6;
    float d = c[0]*pe[0] + c[1]*pe[1] + c[2]*pe[2] + c[3]*pe[3] + c[4]*pe[4] + c[5]*pe[5];
    v[j] = -pt * d;
    mx = fmaxf(mx, v[j]);
  }
  mx = blockMax(mx, red);
  float s = 0.f;
  #pragma unroll
  for (int j = 0; j < 4; j++){ v[j] = __expf(v[j] - mx); s += v[j]; }
  s = blockSum(s, red);
  float inv = 1.f / s;
  #pragma unroll
  for (int j = 0; j < 4; j++) pos[(long long)i*NTOK + tid + j*256] = v[j] * inv;
}

// ------- per-row: softmax(S bf16) -> attn -> entropy -> select -> attnc bf16, heat ----
__global__ __launch_bounds__(256) void rowproc_kernel(
    const __hip_bfloat16* __restrict__ S,
    const float* __restrict__ pos,
    __hip_bfloat16* __restrict__ attnc, // (B,N,N)
    float* __restrict__ heat,           // (B,N)
    const float* __restrict__ gating, const float* __restrict__ h_temp)
{
  int row = blockIdx.x;           // b*N + i
  int b = row >> 10, i = row & 1023;
  int tid = threadIdx.x;
  __shared__ __align__(16) float a0[NTOK];
  __shared__ __align__(16) float a1[NTOK];
  __shared__ float red[4];
  float g = 1.f / (1.f + __expf(-gating[0]));
  float ht = h_temp[0];
  float ent[2];
  const int c0 = tid * 4;
  f32x4 pv = *(const f32x4*)&pos[(long long)i*NTOK + c0];
  #pragma unroll
  for (int k = 0; k < 2; k++){
    const __hip_bfloat16* Sr = S + ((long long)((k*8 + b)*NTOK) + i) * NTOK;
    union { uint2 u; __hip_bfloat16 h[4]; } ld;
    ld.u = *(const uint2*)&Sr[c0];
    f32x4 v;
    #pragma unroll
    for (int j = 0; j < 4; j++) v[j] = __bfloat162float(ld.h[j]);
    float mx = fmaxf(fmaxf(v[0], v[1]), fmaxf(v[2], v[3]));
    mx = blockMax(mx, red);
    float s = 0.f;
    #pragma unroll
    for (int j = 0; j < 4; j++){ v[j] = __expf(v[j] - mx); s += v[j]; }
    s = blockSum(s, red);
    float inv = 1.f / s;
    float e = 0.f;
    float* arow = k ? a1 : a0;
    f32x4 at;
    #pragma unroll
    for (int j = 0; j < 4; j++){
      at[j] = (1.f - g) * (v[j] * inv) + g * pv[j];
      e += -at[j] * __logf(at[j] + 1e-8f);
    }
    *(f32x4*)&arow[c0] = at;
    ent[k] = blockSum(e, red);
  }
  float h0 = 2.f - 2.f / (1.f + __expf(-ht * ent[0]));
  float h1 = 2.f - 2.f / (1.f + __expf(-ht * ent[1]));
  bool fg = (h0 >= h1);
  if (tid == 0) heat[row] = fg ? h0 : h1;
  const float* sel = fg ? a0 : a1;
  f32x4 sv = *(const f32x4*)&sel[c0];
  union { __hip_bfloat16 h[4]; uint2 u; } pk;
  #pragma unroll
  for (int j = 0; j < 4; j++) pk.h[j] = __float2bfloat16(sv[j]);
  *(uint2*)(attnc + ((long long)b*NTOK + i)*NTOK + c0) = pk.u;
}

// ---------------- x,y -> xy bf16 (B,1025,1536) ----------------
__global__ __launch_bounds__(256) void conv_xy_kernel(
    const float* __restrict__ x, const float* __restrict__ y, __hip_bfloat16* __restrict__ xy)
{
  long long idx = (long long)blockIdx.x*256 + threadIdx.x;   // < B*1025*768
  int d = (int)(idx % DIM);
  long long br = idx / DIM;     // b*1025 + r
  int r = (int)(br % NP1);
  xy[br*1536 + d] = __float2bfloat16(x[idx]);
  if (r == 0) xy[br*1536 + DIM + d] = __float2bfloat16(y[idx]);
}

// in fp32 [R][C] -> outT bf16 [C][R]; optional straight outS bf16 [R][C];
// optional scaled transposes outT1/outT2 (|sc1[r]|,|sc2[r]| along original row r)
__global__ __launch_bounds__(256) void transpose_conv_kernel(
    const float* __restrict__ in, long long sIn, int ldin,
    __hip_bfloat16* __restrict__ outT, long long sT,
    __hip_bfloat16* __restrict__ outS, long long sS,
    int R, int C,
    const float* __restrict__ sc1, const float* __restrict__ sc2,
    __hip_bfloat16* __restrict__ outT1, __hip_bfloat16* __restrict__ outT2)
{
  __shared__ float tile[32][33];
  int bx = blockIdx.x, by = blockIdx.y, z = blockIdx.z;
  const float* inb = in + (long long)z*sIn;
  int tx = threadIdx.x & 31, ty = threadIdx.x >> 5;
  #pragma unroll
  for (int p = 0; p < 4; p++){
    int r = by*32 + p*8 + ty;
    int c = bx*32 + tx;
    float v = inb[(long long)r*ldin + c];
    tile[p*8 + ty][tx] = v;
    if (outS) outS[(long long)z*sS + (long long)r*C + c] = __float2bfloat16(v);
  }
  __syncthreads();
  #pragma unroll
  for (int p = 0; p < 4; p++){
    int c = bx*32 + p*8 + ty;   // original col
    int r = by*32 + tx;         // original row
    float v = tile[tx][p*8 + ty];
    long long oidx = (long long)z*sT + (long long)c*R + r;
    outT[oidx] = __float2bfloat16(v);
    if (outT1) outT1[(long long)c*R + r] = __float2bfloat16(v * fabsf(sc1[r]));
    if (outT2) outT2[(long long)c*R + r] = __float2bfloat16(v * fabsf(sc2[r]));
  }
}

// ---------------- bf16 MFMA GEMM (32x32x16, BK=64), BT form, templated tile ----------------
// MT = m-subtiles(32) per wave: block tile = (MT*64) x 128, wave tile = (MT*32) x 64.
// C[z][M][N] = alpha * A[(z&maskA)][M][K] * B[(z>>shiftB)&maskB][N][K]^T  (+ epilogue)
// EPI: 1 = bf16 alpha*acc ; 2 = bf16 gelu(acc+bias) ; 3 = fp32 xres + heatrow*(acc+bias) flat rows
// LDS rows are 64 bf16 (128B); 16B chunks XOR-swizzled by (row&7). K % 64 == 0.
__device__ __forceinline__ void async16(const __bf16* gp, __bf16* lp){
  __builtin_amdgcn_global_load_lds(
      (const __attribute__((address_space(1))) void*)gp,
      (__attribute__((address_space(3))) void*)lp, 16, 0, 0);
}

template<int MT, int EPI>
__global__ __launch_bounds__(256) void mfma_gemm(
    const __bf16* __restrict__ A, const __bf16* __restrict__ Bm, void* __restrict__ Cv,
    int M, int N, int K, int lda, int ldb, int ldc,
    long long sAz, long long sBz, long long sCz,
    int maskA, int shiftB, int maskB, float alpha,
    const float* __restrict__ bias,
    const float* __restrict__ xres,
    const float* __restrict__ heat)
{
  __shared__ __align__(16) __bf16 Atile[MT*64*64];
  __shared__ __align__(16) __bf16 Btile[128*64];

  const int tid  = threadIdx.x;
  const int lane = tid & 63;
  const int wv   = tid >> 6;
  const int wr   = wv >> 1, wc = wv & 1;
  const int n0 = blockIdx.x * 128, m0 = blockIdx.y * (MT*64);
  const int z  = blockIdx.z;

  const __bf16* Ab = A  + (long long)(z & maskA) * sAz;
  const __bf16* Bb = Bm + (long long)((z >> shiftB) & maskB) * sBz;

  // ---- staging: per-lane global pointers (loop-carried), swizzled source chunk ----
  // A: MT*512 chunks -> 2*MT instr of 256; B: 1024 chunks -> 4 instr.
  const __bf16* gA[2*MT]; __bf16* lA[2*MT];
  #pragma unroll
  for (int i = 0; i < 2*MT; i++){
    int s0  = i*256 + wv*64;
    int s   = s0 + lane;
    int row = s >> 3;
    int kc  = (s & 7) ^ (row & 7);
    int gm = m0 + row; if (gm > M-1) gm = M-1;
    gA[i] = Ab + (long long)gm * lda + kc * 8;
    lA[i] = &Atile[s0 * 8];
  }
  const __bf16* gB[4]; __bf16* lB[4];
  #pragma unroll
  for (int i = 0; i < 4; i++){
    int s0  = i*256 + wv*64;
    int s   = s0 + lane;
    int row = s >> 3;
    int kc  = (s & 7) ^ (row & 7);
    int gn = n0 + row; if (gn > N-1) gn = N-1;
    gB[i] = Bb + (long long)gn * ldb + kc * 8;
    lB[i] = &Btile[s0 * 8];
  }

  // ---- fragment read pointers (precomputed, swizzled) ----
  const int fm = lane & 31;        // row within 32-subtile
  const int kq = lane >> 5;        // 8-elem half of each K=16 step
  const __bf16* pA[MT][4]; const __bf16* pB[2][4];
  #pragma unroll
  for (int rr = 0; rr < MT; rr++){
    int rowA = wr*(MT*32) + rr*32 + fm;
    #pragma unroll
    for (int st = 0; st < 4; st++)
      pA[rr][st] = &Atile[rowA*64 + ((st*2 + kq) ^ (rowA & 7)) * 8];
  }
  #pragma unroll
  for (int cc = 0; cc < 2; cc++){
    int rowB = wc*64 + cc*32 + fm;
    #pragma unroll
    for (int st = 0; st < 4; st++)
      pB[cc][st] = &Btile[rowB*64 + ((st*2 + kq) ^ (rowB & 7)) * 8];
  }

  f32x16 acc[MT][2] = {};

  for (int k0 = 0; k0 < K; k0 += 64){
    __syncthreads();
    #pragma unroll
    for (int i = 0; i < 2*MT; i++) async16(gA[i], lA[i]);
    #pragma unroll
    for (int i = 0; i < 4; i++)    async16(gB[i], lB[i]);
    #pragma unroll
    for (int i = 0; i < 2*MT; i++) gA[i] += 64;
    #pragma unroll
    for (int i = 0; i < 4; i++)    gB[i] += 64;
    __syncthreads();
    #pragma unroll
    for (int st = 0; st < 4; st++){
      bf16x8 b0 = *(const bf16x8*)pB[0][st];
      bf16x8 b1 = *(const bf16x8*)pB[1][st];
      #pragma unroll
      for (int rr = 0; rr < MT; rr++){
        bf16x8 a = *(const bf16x8*)pA[rr][st];
        acc[rr][0] = __builtin_amdgcn_mfma_f32_32x32x16_bf16(a, b0, acc[rr][0], 0, 0, 0);
        acc[rr][1] = __builtin_amdgcn_mfma_f32_32x32x16_bf16(a, b1, acc[rr][1], 0, 0, 0);
      }
    }
  }

  // ---- epilogue: C/D layout col=lane&31, row=(reg&3)+8*(reg>>2)+4*(lane>>5) ----
  const int col_l = lane & 31;
  const int row_q = (lane >> 5) * 4;
  #pragma unroll
  for (int rr = 0; rr < MT; rr++){
    #pragma unroll
    for (int cc = 0; cc < 2; cc++){
      int gn  = n0 + wc*64 + cc*32 + col_l;
      if (gn >= N) continue;
      int gmb = m0 + wr*(MT*32) + rr*32 + row_q;
      f32x16 v = acc[rr][cc];
      #pragma unroll
      for (int g = 0; g < 4; g++){
        #pragma unroll
        for (int q = 0; q < 4; q++){
          int gm = gmb + g*8 + q;
          if (gm >= M) continue;
          float cval = alpha * v[g*4 + q];
          long long cidx = (long long)z*sCz + (long long)gm*ldc + gn;
          if (EPI == 1){
            ((__hip_bfloat16*)Cv)[cidx] = __float2bfloat16(cval);
          } else if (EPI == 2){
            float h = cval + bias[gn];
            // tanh-form gelu (max |err| vs exact ~3e-3, below bf16 store rounding)
            float u = 0.7978845608f * (h + 0.044715f * h * h * h);
            float t = 1.f - 2.f / (__expf(2.f * u) + 1.f);
            float ge = 0.5f * h * (1.f + t);
            ((__hip_bfloat16*)Cv)[cidx] = __float2bfloat16(ge);
          } else {
            float h = cval + bias[gn];
            int bq = gm / NP1;
            int rr2 = gm - bq * NP1;
            float f = (rr2 == 0) ? 1.f : heat[bq*NTOK + (rr2 - 1)];
            ((float*)Cv)[cidx] = xres[cidx] + f * h;
          }
        }
      }
    }
  }
}

extern "C" void kernel_launch(void* const* d_in, const int* in_sizes, int n_in,
                              void* d_out, int out_size, void* d_ws, size_t ws_size,
                              hipStream_t stream)
{
  const float* x       = (const float*)d_in[0];
  const float* y       = (const float*)d_in[1];
  const float* coords  = (const float*)d_in[2];
  const float* U       = (const float*)d_in[3];
  const float* S1      = (const float*)d_in[4];
  const float* S2      = (const float*)d_in[5];
  const float* gating  = (const float*)d_in[6];
  const float* h_temp  = (const float*)d_in[7];
  const float* p_temp  = (const float*)d_in[8];
  const float* pos_emb = (const float*)d_in[9];
  const float* W1      = (const float*)d_in[10];
  const float* b1      = (const float*)d_in[11];
  const float* W2      = (const float*)d_in[12];
  const float* b2      = (const float*)d_in[13];
  float* out = (float*)d_out;
  char* ws = (char*)d_ws;

  size_t off = 0;
  auto alloc = [&](size_t bytes){ size_t r = off; off = (off + bytes + 255) & ~(size_t)255; return r; };
  const long long NN  = (long long)NTOK * NTOK;
  const long long DD  = (long long)DIM * DIM;
  const size_t o_pos  = alloc(NN * 4);                       // pos fp32
  const size_t o_S    = alloc((size_t)BB*NP1*DFF * 2);       // hg bf16 region; S bf16 (32MB) overlays start
  const size_t o_xy   = alloc((size_t)BB*NP1*1536 * 2);      // xy bf16
  const size_t o_yb   = alloc((size_t)BB*NTOK*DIM * 2);      // yb bf16
  const size_t o_ybT  = alloc((size_t)BB*DIM*NTOK * 2);      // ybT bf16
  const size_t o_xs   = alloc((size_t)2*BB*NTOK*DIM * 2);    // xs bf16 (k,b,N,D)
  const size_t o_attn = alloc((size_t)BB*NN * 2);            // attnc bf16
  const size_t o_UT   = alloc((size_t)DD * 2);
  const size_t o_UTs  = alloc((size_t)2*DD * 2);             // UTs1,UTs2
  const size_t o_Mk   = alloc((size_t)2*DD * 2);             // M1,M2 bf16
  const size_t o_W1T  = alloc((size_t)DFF*2*DIM * 2);
  const size_t o_W2T  = alloc((size_t)DIM*DFF * 2);
  const size_t o_heat = alloc((size_t)BB*NTOK * 4);

  __hip_bfloat16* S_bf = (__hip_bfloat16*)(ws + o_S);        // (2,B,N,N) bf16
  __hip_bfloat16* hg   = (__hip_bfloat16*)(ws + o_S);        // overlay (post-rowproc)
  __hip_bfloat16* xy   = (__hip_bfloat16*)(ws + o_xy);
  __hip_bfloat16* yb   = (__hip_bfloat16*)(ws + o_yb);
  __hip_bfloat16* ybT  = (__hip_bfloat16*)(ws + o_ybT);
  __hip_bfloat16* xs   = (__hip_bfloat16*)(ws + o_xs);
  __hip_bfloat16* attnc= (__hip_bfloat16*)(ws + o_attn);
  __hip_bfloat16* UT   = (__hip_bfloat16*)(ws + o_UT);
  __hip_bfloat16* UTs  = (__hip_bfloat16*)(ws + o_UTs);
  __hip_bfloat16* Mk   = (__hip_bfloat16*)(ws + o_Mk);
  __hip_bfloat16* W1T  = (__hip_bfloat16*)(ws + o_W1T);
  __hip_bfloat16* W2T  = (__hip_bfloat16*)(ws + o_W2T);
  float* pos  = (float*)(ws + o_pos);
  float* heat = (float*)(ws + o_heat);

  const float scale = 0.03608439182435161f; // 768^-0.5
  dim3 blk(256);

  // ---- prep ----
  pos_kernel<<<dim3(NTOK), blk, 0, stream>>>(coords, pos_emb, p_temp, pos);
  conv_xy_kernel<<<dim3((BB*NP1*DIM)/256), blk, 0, stream>>>(x, y, xy);
  transpose_conv_kernel<<<dim3(DIM/32, DIM/32, 1), blk, 0, stream>>>(
      U, 0LL, DIM, UT, 0LL, nullptr, 0LL, DIM, DIM, S1, S2, UTs, UTs + DD);
  transpose_conv_kernel<<<dim3(DFF/32, (2*DIM)/32, 1), blk, 0, stream>>>(
      W1, 0LL, DFF, W1T, 0LL, nullptr, 0LL, 2*DIM, DFF, nullptr, nullptr, nullptr, nullptr);
  transpose_conv_kernel<<<dim3(DIM/32, DFF/32, 1), blk, 0, stream>>>(
      W2, 0LL, DIM, W2T, 0LL, nullptr, 0LL, DFF, DIM, nullptr, nullptr, nullptr, nullptr);
  transpose_conv_kernel<<<dim3(DIM/32, NTOK/32, BB), blk, 0, stream>>>(
      y + DIM, (long long)NP1*DIM, DIM, ybT, (long long)DIM*NTOK, yb, (long long)NTOK*DIM,
      NTOK, DIM, nullptr, nullptr, nullptr, nullptr);

  // ---- G1: M_k = UT @ UTs_k^T (symmetric), z=2 ---- (256x128 tile)
  mfma_gemm<4,1><<<dim3(DIM/128, DIM/256, 2), blk, 0, stream>>>(
      (const __bf16*)UT, (const __bf16*)UTs, Mk,
      DIM, DIM, DIM, DIM, DIM, DIM,
      0LL, DD, DD, 0, 0, 1, 1.f, nullptr, nullptr, nullptr);

  // ---- G2: xs[k,b] = xb[b] @ M_k^T, z=k*8+b ---- (256x128)
  mfma_gemm<4,1><<<dim3(DIM/128, NTOK/256, 16), blk, 0, stream>>>(
      (const __bf16*)(xy + 1536), (const __bf16*)Mk, xs,
      NTOK, DIM, DIM, 1536, DIM, DIM,
      (long long)NP1*1536, DD, (long long)NTOK*DIM,
      7, 3, 1, 1.f, nullptr, nullptr, nullptr);

  // ---- G3: S[k,b] = bf16( scale * xs[k,b] @ yb[b]^T ) ---- (256x128)
  mfma_gemm<4,1><<<dim3(NTOK/128, NTOK/256, 16), blk, 0, stream>>>(
      (const __bf16*)xs, (const __bf16*)yb, S_bf,
      NTOK, NTOK, DIM, DIM, DIM, NTOK,
      (long long)NTOK*DIM, (long long)NTOK*DIM, NN,
      15, 0, 7, scale, nullptr, nullptr, nullptr);

  // ---- rowproc: softmax + mix + entropy + select ----
  rowproc_kernel<<<dim3(BB*NTOK), blk, 0, stream>>>(S_bf, pos, attnc, heat, gating, h_temp);

  // ---- G4: y_out[b] = attnc[b] @ ybT[b]^T -> xy cols 768.., rows 1.. ---- (128x128, keep grid deep)
  mfma_gemm<2,1><<<dim3(DIM/128, NTOK/128, BB), blk, 0, stream>>>(
      (const __bf16*)attnc, (const __bf16*)ybT, xy + 1536 + DIM,
      NTOK, DIM, NTOK, NTOK, NTOK, 1536,
      NN, (long long)DIM*NTOK, (long long)NP1*1536,
      7, 0, 7, 1.f, nullptr, nullptr, nullptr);

  // ---- G5: hg = gelu(xy @ W1T^T + b1), flattened M=8200 ---- (256x128)
  mfma_gemm<4,2><<<dim3(DFF/128, (BB*NP1 + 255)/256, 1), blk, 0, stream>>>(
      (const __bf16*)xy, (const __bf16*)W1T, hg,
      BB*NP1, DFF, 2*DIM, 1536, 1536, DFF,
      0LL, 0LL, 0LL, 0, 0, 0, 1.f, b1, nullptr, nullptr);

  // ---- G6: out = x + heatrow*(hg @ W2T^T + b2), flattened M=8200 ---- (128x128, N=768 limits grid)
  mfma_gemm<2,3><<<dim3(DIM/128, (BB*NP1 + 127)/128, 1), blk, 0, stream>>>(
      (const __bf16*)hg, (const __bf16*)W2T, out,
      BB*NP1, DIM, DFF, DFF, DFF, DIM,
      0LL, 0LL, 0LL, 0, 0, 0, 1.f, b2, x, heat);
}

// Round 7
// 624.952 us; speedup vs baseline: 1.1175x; 1.1175x over previous
//
#include <hip/hip_runtime.h>
#include <hip/hip_bf16.h>
#include <math.h>

#define BB   8
#define NTOK 1024
#define DIM  768
#define DFF  3072
#define NP1  1025

typedef __bf16 bf16x8 __attribute__((ext_vector_type(8)));
typedef float  f32x4  __attribute__((ext_vector_type(4)));
typedef float  f32x16 __attribute__((ext_vector_type(16)));

// ---------------- reductions (wave = 64) ----------------
__device__ __forceinline__ float waveMax(float v){
  #pragma unroll
  for (int o = 32; o > 0; o >>= 1) v = fmaxf(v, __shfl_down(v, o, 64));
  return v;
}
__device__ __forceinline__ float waveSum(float v){
  #pragma unroll
  for (int o = 32; o > 0; o >>= 1) v += __shfl_down(v, o, 64);
  return v;
}
__device__ __forceinline__ float blockMax(float v, float* red){
  int lane = threadIdx.x & 63, w = threadIdx.x >> 6;
  v = waveMax(v);
  if (lane == 0) red[w] = v;
  __syncthreads();
  float r = fmaxf(fmaxf(red[0], red[1]), fmaxf(red[2], red[3]));
  __syncthreads();
  return r;
}
__device__ __forceinline__ float blockSum(float v, float* red){
  int lane = threadIdx.x & 63, w = threadIdx.x >> 6;
  v = waveSum(v);
  if (lane == 0) red[w] = v;
  __syncthreads();
  float r = red[0] + red[1] + red[2] + red[3];
  __syncthreads();
  return r;
}

// ---------------- pos softmax ----------------
__global__ __launch_bounds__(256) void pos_kernel(
    const float* __restrict__ coords, const float* __restrict__ pos_emb,
    const float* __restrict__ p_temp, float* __restrict__ pos)
{
  int i = blockIdx.x;
  int tid = threadIdx.x;
  __shared__ float red[4];
  __shared__ float pe[6];
  if (tid < 6) pe[tid] = pos_emb[i*6 + tid];
  __syncthreads();
  float pt = fabsf(p_temp[0]);
  float v[4]; float mx = -INFINITY;
  #pragma unroll
  for (int j = 0; j < 4; j++){
    int jj = tid + j*256;
    const float* c = coords + ((long long)i*NTOK + jj)*6;
    float d = c[0]*pe[0] + c[1]*pe[1] + c[2]*pe[2] + c[3]*pe[3] + c[4]*pe[4] + c[5]*pe[5];
    v[j] = -pt * d;
    mx = fmaxf(mx, v[j]);
  }
  mx = blockMax(mx, red);
  float s = 0.f;
  #pragma unroll
  for (int j = 0; j < 4; j++){ v[j] = __expf(v[j] - mx); s += v[j]; }
  s = blockSum(s, red);
  float inv = 1.f / s;
  #pragma unroll
  for (int j = 0; j < 4; j++) pos[(long long)i*NTOK + tid + j*256] = v[j] * inv;
}

// ------- per-row: softmax(S bf16) -> attn -> entropy -> select -> attnc bf16, heat ----
__global__ __launch_bounds__(256) void rowproc_kernel(
    const __hip_bfloat16* __restrict__ S,
    const float* __restrict__ pos,
    __hip_bfloat16* __restrict__ attnc, // (B,N,N)
    float* __restrict__ heat,           // (B,N)
    const float* __restrict__ gating, const float* __restrict__ h_temp)
{
  int row = blockIdx.x;           // b*N + i
  int b = row >> 10, i = row & 1023;
  int tid = threadIdx.x;
  __shared__ __align__(16) float a0[NTOK];
  __shared__ __align__(16) float a1[NTOK];
  __shared__ float red[4];
  float g = 1.f / (1.f + __expf(-gating[0]));
  float ht = h_temp[0];
  float ent[2];
  const int c0 = tid * 4;
  f32x4 pv = *(const f32x4*)&pos[(long long)i*NTOK + c0];
  #pragma unroll
  for (int k = 0; k < 2; k++){
    const __hip_bfloat16* Sr = S + ((long long)((k*8 + b)*NTOK) + i) * NTOK;
    union { uint2 u; __hip_bfloat16 h[4]; } ld;
    ld.u = *(const uint2*)&Sr[c0];
    f32x4 v;
    #pragma unroll
    for (int j = 0; j < 4; j++) v[j] = __bfloat162float(ld.h[j]);
    float mx = fmaxf(fmaxf(v[0], v[1]), fmaxf(v[2], v[3]));
    mx = blockMax(mx, red);
    float s = 0.f;
    #pragma unroll
    for (int j = 0; j < 4; j++){ v[j] = __expf(v[j] - mx); s += v[j]; }
    s = blockSum(s, red);
    float inv = 1.f / s;
    float e = 0.f;
    float* arow = k ? a1 : a0;
    f32x4 at;
    #pragma unroll
    for (int j = 0; j < 4; j++){
      at[j] = (1.f - g) * (v[j] * inv) + g * pv[j];
      e += -at[j] * __logf(at[j] + 1e-8f);
    }
    *(f32x4*)&arow[c0] = at;
    ent[k] = blockSum(e, red);
  }
  float h0 = 2.f - 2.f / (1.f + __expf(-ht * ent[0]));
  float h1 = 2.f - 2.f / (1.f + __expf(-ht * ent[1]));
  bool fg = (h0 >= h1);
  if (tid == 0) heat[row] = fg ? h0 : h1;
  const float* sel = fg ? a0 : a1;
  f32x4 sv = *(const f32x4*)&sel[c0];
  union { __hip_bfloat16 h[4]; uint2 u; } pk;
  #pragma unroll
  for (int j = 0; j < 4; j++) pk.h[j] = __float2bfloat16(sv[j]);
  *(uint2*)(attnc + ((long long)b*NTOK + i)*NTOK + c0) = pk.u;
}

// ---------------- x,y -> xy bf16 (B,1025,1536) ----------------
__global__ __launch_bounds__(256) void conv_xy_kernel(
    const float* __restrict__ x, const float* __restrict__ y, __hip_bfloat16* __restrict__ xy)
{
  long long idx = (long long)blockIdx.x*256 + threadIdx.x;   // < B*1025*768
  int d = (int)(idx % DIM);
  long long br = idx / DIM;     // b*1025 + r
  int r = (int)(br % NP1);
  xy[br*1536 + d] = __float2bfloat16(x[idx]);
  if (r == 0) xy[br*1536 + DIM + d] = __float2bfloat16(y[idx]);
}

// in fp32 [R][C] -> outT bf16 [C][R]; optional straight outS bf16 [R][C];
// optional scaled transposes outT1/outT2 (|sc1[r]|,|sc2[r]| along original row r)
__global__ __launch_bounds__(256) void transpose_conv_kernel(
    const float* __restrict__ in, long long sIn, int ldin,
    __hip_bfloat16* __restrict__ outT, long long sT,
    __hip_bfloat16* __restrict__ outS, long long sS,
    int R, int C,
    const float* __restrict__ sc1, const float* __restrict__ sc2,
    __hip_bfloat16* __restrict__ outT1, __hip_bfloat16* __restrict__ outT2)
{
  __shared__ float tile[32][33];
  int bx = blockIdx.x, by = blockIdx.y, z = blockIdx.z;
  const float* inb = in + (long long)z*sIn;
  int tx = threadIdx.x & 31, ty = threadIdx.x >> 5;
  #pragma unroll
  for (int p = 0; p < 4; p++){
    int r = by*32 + p*8 + ty;
    int c = bx*32 + tx;
    float v = inb[(long long)r*ldin + c];
    tile[p*8 + ty][tx] = v;
    if (outS) outS[(long long)z*sS + (long long)r*C + c] = __float2bfloat16(v);
  }
  __syncthreads();
  #pragma unroll
  for (int p = 0; p < 4; p++){
    int c = bx*32 + p*8 + ty;   // original col
    int r = by*32 + tx;         // original row
    float v = tile[tx][p*8 + ty];
    long long oidx = (long long)z*sT + (long long)c*R + r;
    outT[oidx] = __float2bfloat16(v);
    if (outT1) outT1[(long long)c*R + r] = __float2bfloat16(v * fabsf(sc1[r]));
    if (outT2) outT2[(long long)c*R + r] = __float2bfloat16(v * fabsf(sc2[r]));
  }
}

// ---------------- bf16 MFMA GEMM (32x32x16), BT form, double-buffered BK=32 ----------------
// Block tile 128x128, wave tile 64x64 (acc 2x2 of 32x32 => 64 AGPR).
// C[z][M][N] = alpha * A[(z&maskA)][M][K] * B[(z>>shiftB)&maskB][N][K]^T  (+ epilogue)
// EPI: 1 = bf16 alpha*acc ; 2 = bf16 gelu(acc+bias) ; 3 = fp32 xres + heatrow*(acc+bias) flat rows
// LDS: two 16KB buffers (A 8KB + B 8KB each). Rows are 32 bf16 (64B, 4x16B chunks),
// chunks XOR-swizzled by (row&3). One barrier per 32-K tile; loads for tile t+1 are
// issued right after the barrier so they stay in flight across tile t's MFMA phase
// (the next barrier's vmcnt drain lands one full compute-phase later). K % 64 == 0.
__device__ __forceinline__ void async16(const __bf16* gp, __bf16* lp){
  __builtin_amdgcn_global_load_lds(
      (const __attribute__((address_space(1))) void*)gp,
      (__attribute__((address_space(3))) void*)lp, 16, 0, 0);
}

template<int EPI>
__global__ __launch_bounds__(256) void mfma_gemm(
    const __bf16* __restrict__ A, const __bf16* __restrict__ Bm, void* __restrict__ Cv,
    int M, int N, int K, int lda, int ldb, int ldc,
    long long sAz, long long sBz, long long sCz,
    int maskA, int shiftB, int maskB, float alpha,
    const float* __restrict__ bias,
    const float* __restrict__ xres,
    const float* __restrict__ heat)
{
  // [buf][128 rows][32 bf16]
  __shared__ __align__(16) __bf16 Atile[2][128*32];
  __shared__ __align__(16) __bf16 Btile[2][128*32];

  const int tid  = threadIdx.x;
  const int lane = tid & 63;
  const int wv   = tid >> 6;
  const int wr   = wv >> 1, wc = wv & 1;
  const int n0 = blockIdx.x * 128, m0 = blockIdx.y * 128;
  const int z  = blockIdx.z;

  const __bf16* Ab = A  + (long long)(z & maskA) * sAz;
  const __bf16* Bb = Bm + (long long)((z >> shiftB) & maskB) * sBz;

  // ---- staging: 512 16B-chunks per matrix per tile; wave wv instr i covers slots [(i*4+wv)*64,+64) ----
  const __bf16* gA[2]; const __bf16* gB[2];
  __bf16 *lA0[2], *lA1[2], *lB0[2], *lB1[2];
  #pragma unroll
  for (int i = 0; i < 2; i++){
    int s0  = i*256 + wv*64;
    int s   = s0 + lane;
    int row = s >> 2;
    int kc  = (s & 3) ^ (row & 3);   // physical slot s holds global chunk kc
    int gm = m0 + row; if (gm > M-1) gm = M-1;
    int gn = n0 + row; if (gn > N-1) gn = N-1;
    gA[i] = Ab + (long long)gm * lda + kc * 8;
    gB[i] = Bb + (long long)gn * ldb + kc * 8;
    lA0[i] = &Atile[0][s0 * 8];  lA1[i] = &Atile[1][s0 * 8];
    lB0[i] = &Btile[0][s0 * 8];  lB1[i] = &Btile[1][s0 * 8];
  }

  // ---- fragment read pointers into buf0 (buf1 = +4096 elements, folds into ds offset) ----
  const int fm = lane & 31;        // row within 32-subtile
  const int kq = lane >> 5;        // 8-elem half of each K=16 step
  const __bf16* pA[2][2]; const __bf16* pB[2][2];
  #pragma unroll
  for (int rr = 0; rr < 2; rr++){
    int rowA = wr*64 + rr*32 + fm;
    int rowB = wc*64 + rr*32 + fm;
    #pragma unroll
    for (int st = 0; st < 2; st++){
      pA[rr][st] = &Atile[0][rowA*32 + ((st*2 + kq) ^ (rowA & 3)) * 8];
      pB[rr][st] = &Btile[0][rowB*32 + ((st*2 + kq) ^ (rowB & 3)) * 8];
    }
  }

  f32x16 acc[2][2] = {};

  const int nIter = K >> 5;          // 32-K tiles; nIter is even (K % 64 == 0)

  // prologue: tile 0 -> buf0
  #pragma unroll
  for (int i = 0; i < 2; i++){ async16(gA[i], lA0[i]); async16(gB[i], lB0[i]); gA[i] += 32; gB[i] += 32; }

  for (int t = 0; t < nIter; t += 2){
    // ---- tile t (buf0) ----
    __syncthreads();                  // drains tile-t loads (in flight since last iter/prologue)
    #pragma unroll
    for (int i = 0; i < 2; i++){ async16(gA[i], lA1[i]); async16(gB[i], lB1[i]); gA[i] += 32; gB[i] += 32; }
    #pragma unroll
    for (int st = 0; st < 2; st++){
      bf16x8 b0 = *(const bf16x8*)(pB[0][st]);
      bf16x8 b1 = *(const bf16x8*)(pB[1][st]);
      bf16x8 a0 = *(const bf16x8*)(pA[0][st]);
      bf16x8 a1 = *(const bf16x8*)(pA[1][st]);
      acc[0][0] = __builtin_amdgcn_mfma_f32_32x32x16_bf16(a0, b0, acc[0][0], 0, 0, 0);
      acc[0][1] = __builtin_amdgcn_mfma_f32_32x32x16_bf16(a0, b1, acc[0][1], 0, 0, 0);
      acc[1][0] = __builtin_amdgcn_mfma_f32_32x32x16_bf16(a1, b0, acc[1][0], 0, 0, 0);
      acc[1][1] = __builtin_amdgcn_mfma_f32_32x32x16_bf16(a1, b1, acc[1][1], 0, 0, 0);
    }
    // ---- tile t+1 (buf1) ----
    __syncthreads();                  // drains tile-(t+1) loads (in flight across tile-t MFMA)
    if (t + 2 < nIter){
      #pragma unroll
      for (int i = 0; i < 2; i++){ async16(gA[i], lA0[i]); async16(gB[i], lB0[i]); gA[i] += 32; gB[i] += 32; }
    }
    #pragma unroll
    for (int st = 0; st < 2; st++){
      bf16x8 b0 = *(const bf16x8*)(pB[0][st] + 4096);
      bf16x8 b1 = *(const bf16x8*)(pB[1][st] + 4096);
      bf16x8 a0 = *(const bf16x8*)(pA[0][st] + 4096);
      bf16x8 a1 = *(const bf16x8*)(pA[1][st] + 4096);
      acc[0][0] = __builtin_amdgcn_mfma_f32_32x32x16_bf16(a0, b0, acc[0][0], 0, 0, 0);
      acc[0][1] = __builtin_amdgcn_mfma_f32_32x32x16_bf16(a0, b1, acc[0][1], 0, 0, 0);
      acc[1][0] = __builtin_amdgcn_mfma_f32_32x32x16_bf16(a1, b0, acc[1][0], 0, 0, 0);
      acc[1][1] = __builtin_amdgcn_mfma_f32_32x32x16_bf16(a1, b1, acc[1][1], 0, 0, 0);
    }
  }

  // ---- epilogue: C/D layout col=lane&31, row=(reg&3)+8*(reg>>2)+4*(lane>>5) ----
  const int col_l = lane & 31;
  const int row_q = (lane >> 5) * 4;
  #pragma unroll
  for (int rr = 0; rr < 2; rr++){
    #pragma unroll
    for (int cc = 0; cc < 2; cc++){
      int gn  = n0 + wc*64 + cc*32 + col_l;
      if (gn >= N) continue;
      int gmb = m0 + wr*64 + rr*32 + row_q;
      f32x16 v = acc[rr][cc];
      #pragma unroll
      for (int g = 0; g < 4; g++){
        #pragma unroll
        for (int q = 0; q < 4; q++){
          int gm = gmb + g*8 + q;
          if (gm >= M) continue;
          float cval = alpha * v[g*4 + q];
          long long cidx = (long long)z*sCz + (long long)gm*ldc + gn;
          if (EPI == 1){
            ((__hip_bfloat16*)Cv)[cidx] = __float2bfloat16(cval);
          } else if (EPI == 2){
            float h = cval + bias[gn];
            // tanh-form gelu (max |err| vs exact ~3e-3, below bf16 store rounding)
            float u = 0.7978845608f * (h + 0.044715f * h * h * h);
            float tt = 1.f - 2.f / (__expf(2.f * u) + 1.f);
            float ge = 0.5f * h * (1.f + tt);
            ((__hip_bfloat16*)Cv)[cidx] = __float2bfloat16(ge);
          } else {
            float h = cval + bias[gn];
            int bq = gm / NP1;
            int rr2 = gm - bq * NP1;
            float f = (rr2 == 0) ? 1.f : heat[bq*NTOK + (rr2 - 1)];
            ((float*)Cv)[cidx] = xres[cidx] + f * h;
          }
        }
      }
    }
  }
}

extern "C" void kernel_launch(void* const* d_in, const int* in_sizes, int n_in,
                              void* d_out, int out_size, void* d_ws, size_t ws_size,
                              hipStream_t stream)
{
  const float* x       = (const float*)d_in[0];
  const float* y       = (const float*)d_in[1];
  const float* coords  = (const float*)d_in[2];
  const float* U       = (const float*)d_in[3];
  const float* S1      = (const float*)d_in[4];
  const float* S2      = (const float*)d_in[5];
  const float* gating  = (const float*)d_in[6];
  const float* h_temp  = (const float*)d_in[7];
  const float* p_temp  = (const float*)d_in[8];
  const float* pos_emb = (const float*)d_in[9];
  const float* W1      = (const float*)d_in[10];
  const float* b1      = (const float*)d_in[11];
  const float* W2      = (const float*)d_in[12];
  const float* b2      = (const float*)d_in[13];
  float* out = (float*)d_out;
  char* ws = (char*)d_ws;

  size_t off = 0;
  auto alloc = [&](size_t bytes){ size_t r = off; off = (off + bytes + 255) & ~(size_t)255; return r; };
  const long long NN  = (long long)NTOK * NTOK;
  const long long DD  = (long long)DIM * DIM;
  const size_t o_pos  = alloc(NN * 4);                       // pos fp32
  const size_t o_S    = alloc((size_t)BB*NP1*DFF * 2);       // hg bf16 region; S bf16 (32MB) overlays start
  const size_t o_xy   = alloc((size_t)BB*NP1*1536 * 2);      // xy bf16
  const size_t o_yb   = alloc((size_t)BB*NTOK*DIM * 2);      // yb bf16
  const size_t o_ybT  = alloc((size_t)BB*DIM*NTOK * 2);      // ybT bf16
  const size_t o_xs   = alloc((size_t)2*BB*NTOK*DIM * 2);    // xs bf16 (k,b,N,D)
  const size_t o_attn = alloc((size_t)BB*NN * 2);            // attnc bf16
  const size_t o_UT   = alloc((size_t)DD * 2);
  const size_t o_UTs  = alloc((size_t)2*DD * 2);             // UTs1,UTs2
  const size_t o_Mk   = alloc((size_t)2*DD * 2);             // M1,M2 bf16
  const size_t o_W1T  = alloc((size_t)DFF*2*DIM * 2);
  const size_t o_W2T  = alloc((size_t)DIM*DFF * 2);
  const size_t o_heat = alloc((size_t)BB*NTOK * 4);

  __hip_bfloat16* S_bf = (__hip_bfloat16*)(ws + o_S);        // (2,B,N,N) bf16
  __hip_bfloat16* hg   = (__hip_bfloat16*)(ws + o_S);        // overlay (post-rowproc)
  __hip_bfloat16* xy   = (__hip_bfloat16*)(ws + o_xy);
  __hip_bfloat16* yb   = (__hip_bfloat16*)(ws + o_yb);
  __hip_bfloat16* ybT  = (__hip_bfloat16*)(ws + o_ybT);
  __hip_bfloat16* xs   = (__hip_bfloat16*)(ws + o_xs);
  __hip_bfloat16* attnc= (__hip_bfloat16*)(ws + o_attn);
  __hip_bfloat16* UT   = (__hip_bfloat16*)(ws + o_UT);
  __hip_bfloat16* UTs  = (__hip_bfloat16*)(ws + o_UTs);
  __hip_bfloat16* Mk   = (__hip_bfloat16*)(ws + o_Mk);
  __hip_bfloat16* W1T  = (__hip_bfloat16*)(ws + o_W1T);
  __hip_bfloat16* W2T  = (__hip_bfloat16*)(ws + o_W2T);
  float* pos  = (float*)(ws + o_pos);
  float* heat = (float*)(ws + o_heat);

  const float scale = 0.03608439182435161f; // 768^-0.5
  dim3 blk(256);

  // ---- prep ----
  pos_kernel<<<dim3(NTOK), blk, 0, stream>>>(coords, pos_emb, p_temp, pos);
  conv_xy_kernel<<<dim3((BB*NP1*DIM)/256), blk, 0, stream>>>(x, y, xy);
  transpose_conv_kernel<<<dim3(DIM/32, DIM/32, 1), blk, 0, stream>>>(
      U, 0LL, DIM, UT, 0LL, nullptr, 0LL, DIM, DIM, S1, S2, UTs, UTs + DD);
  transpose_conv_kernel<<<dim3(DFF/32, (2*DIM)/32, 1), blk, 0, stream>>>(
      W1, 0LL, DFF, W1T, 0LL, nullptr, 0LL, 2*DIM, DFF, nullptr, nullptr, nullptr, nullptr);
  transpose_conv_kernel<<<dim3(DIM/32, DFF/32, 1), blk, 0, stream>>>(
      W2, 0LL, DIM, W2T, 0LL, nullptr, 0LL, DFF, DIM, nullptr, nullptr, nullptr, nullptr);
  transpose_conv_kernel<<<dim3(DIM/32, NTOK/32, BB), blk, 0, stream>>>(
      y + DIM, (long long)NP1*DIM, DIM, ybT, (long long)DIM*NTOK, yb, (long long)NTOK*DIM,
      NTOK, DIM, nullptr, nullptr, nullptr, nullptr);

  // ---- G1: M_k = UT @ UTs_k^T (symmetric), z=2 ----
  mfma_gemm<1><<<dim3(DIM/128, DIM/128, 2), blk, 0, stream>>>(
      (const __bf16*)UT, (const __bf16*)UTs, Mk,
      DIM, DIM, DIM, DIM, DIM, DIM,
      0LL, DD, DD, 0, 0, 1, 1.f, nullptr, nullptr, nullptr);

  // ---- G2: xs[k,b] = xb[b] @ M_k^T, z=k*8+b ----
  mfma_gemm<1><<<dim3(DIM/128, NTOK/128, 16), blk, 0, stream>>>(
      (const __bf16*)(xy + 1536), (const __bf16*)Mk, xs,
      NTOK, DIM, DIM, 1536, DIM, DIM,
      (long long)NP1*1536, DD, (long long)NTOK*DIM,
      7, 3, 1, 1.f, nullptr, nullptr, nullptr);

  // ---- G3: S[k,b] = bf16( scale * xs[k,b] @ yb[b]^T ) ----
  mfma_gemm<1><<<dim3(NTOK/128, NTOK/128, 16), blk, 0, stream>>>(
      (const __bf16*)xs, (const __bf16*)yb, S_bf,
      NTOK, NTOK, DIM, DIM, DIM, NTOK,
      (long long)NTOK*DIM, (long long)NTOK*DIM, NN,
      15, 0, 7, scale, nullptr, nullptr, nullptr);

  // ---- rowproc: softmax + mix + entropy + select ----
  rowproc_kernel<<<dim3(BB*NTOK), blk, 0, stream>>>(S_bf, pos, attnc, heat, gating, h_temp);

  // ---- G4: y_out[b] = attnc[b] @ ybT[b]^T -> xy cols 768.., rows 1.. ----
  mfma_gemm<1><<<dim3(DIM/128, NTOK/128, BB), blk, 0, stream>>>(
      (const __bf16*)attnc, (const __bf16*)ybT, xy + 1536 + DIM,
      NTOK, DIM, NTOK, NTOK, NTOK, 1536,
      NN, (long long)DIM*NTOK, (long long)NP1*1536,
      7, 0, 7, 1.f, nullptr, nullptr, nullptr);

  // ---- G5: hg = gelu(xy @ W1T^T + b1), flattened M=8200 ----
  mfma_gemm<2><<<dim3(DFF/128, (BB*NP1 + 127)/128, 1), blk, 0, stream>>>(
      (const __bf16*)xy, (const __bf16*)W1T, hg,
      BB*NP1, DFF, 2*DIM, 1536, 1536, DFF,
      0LL, 0LL, 0LL, 0, 0, 0, 1.f, b1, nullptr, nullptr);

  // ---- G6: out = x + heatrow*(hg @ W2T^T + b2), flattened M=8200 ----
  mfma_gemm<3><<<dim3(DIM/128, (BB*NP1 + 127)/128, 1), blk, 0, stream>>>(
      (const __bf16*)hg, (const __bf16*)W2T, out,
      BB*NP1, DIM, DFF, DFF, DFF, DIM,
      0LL, 0LL, 0LL, 0, 0, 0, 1.f, b2, x, heat);
}

// Round 8
// 526.450 us; speedup vs baseline: 1.3265x; 1.1871x over previous
//
#include <hip/hip_runtime.h>
#include <hip/hip_bf16.h>
#include <math.h>

#define BB   8
#define NTOK 1024
#define DIM  768
#define DFF  3072
#define NP1  1025

typedef __bf16 bf16x8 __attribute__((ext_vector_type(8)));
typedef float  f32x4  __attribute__((ext_vector_type(4)));
typedef float  f32x16 __attribute__((ext_vector_type(16)));

// ---------------- reductions (wave = 64) ----------------
__device__ __forceinline__ float waveMax(float v){
  #pragma unroll
  for (int o = 32; o > 0; o >>= 1) v = fmaxf(v, __shfl_down(v, o, 64));
  return v;
}
__device__ __forceinline__ float waveSum(float v){
  #pragma unroll
  for (int o = 32; o > 0; o >>= 1) v += __shfl_down(v, o, 64);
  return v;
}
__device__ __forceinline__ float blockMax(float v, float* red){
  int lane = threadIdx.x & 63, w = threadIdx.x >> 6;
  v = waveMax(v);
  if (lane == 0) red[w] = v;
  __syncthreads();
  float r = fmaxf(fmaxf(red[0], red[1]), fmaxf(red[2], red[3]));
  __syncthreads();
  return r;
}
__device__ __forceinline__ float blockSum(float v, float* red){
  int lane = threadIdx.x & 63, w = threadIdx.x >> 6;
  v = waveSum(v);
  if (lane == 0) red[w] = v;
  __syncthreads();
  float r = red[0] + red[1] + red[2] + red[3];
  __syncthreads();
  return r;
}

// ---------------- pos softmax (bf16 out) ----------------
__global__ __launch_bounds__(256) void pos_kernel(
    const float* __restrict__ coords, const float* __restrict__ pos_emb,
    const float* __restrict__ p_temp, __hip_bfloat16* __restrict__ pos)
{
  int i = blockIdx.x;
  int tid = threadIdx.x;
  __shared__ float red[4];
  __shared__ float pe[6];
  if (tid < 6) pe[tid] = pos_emb[i*6 + tid];
  __syncthreads();
  float pt = fabsf(p_temp[0]);
  float v[4]; float mx = -INFINITY;
  #pragma unroll
  for (int j = 0; j < 4; j++){
    int jj = tid + j*256;
    const float* c = coords + ((long long)i*NTOK + jj)*6;
    float d = c[0]*pe[0] + c[1]*pe[1] + c[2]*pe[2] + c[3]*pe[3] + c[4]*pe[4] + c[5]*pe[5];
    v[j] = -pt * d;
    mx = fmaxf(mx, v[j]);
  }
  mx = blockMax(mx, red);
  float s = 0.f;
  #pragma unroll
  for (int j = 0; j < 4; j++){ v[j] = __expf(v[j] - mx); s += v[j]; }
  s = blockSum(s, red);
  float inv = 1.f / s;
  #pragma unroll
  for (int j = 0; j < 4; j++) pos[(long long)i*NTOK + tid + j*256] = __float2bfloat16(v[j] * inv);
}

// ------- per-row: softmax(S bf16) -> attn -> entropy -> select -> attnc bf16, heat ----
__global__ __launch_bounds__(256) void rowproc_kernel(
    const __hip_bfloat16* __restrict__ S,
    const __hip_bfloat16* __restrict__ pos,
    __hip_bfloat16* __restrict__ attnc, // (B,N,N)
    float* __restrict__ heat,           // (B,N)
    const float* __restrict__ gating, const float* __restrict__ h_temp)
{
  int row = blockIdx.x;           // b*N + i
  int b = row >> 10, i = row & 1023;
  int tid = threadIdx.x;
  __shared__ __align__(16) float a0[NTOK];
  __shared__ __align__(16) float a1[NTOK];
  __shared__ float red[4];
  float g = 1.f / (1.f + __expf(-gating[0]));
  float ht = h_temp[0];
  float ent[2];
  const int c0 = tid * 4;
  union { uint2 u; __hip_bfloat16 h[4]; } pld;
  pld.u = *(const uint2*)&pos[(long long)i*NTOK + c0];
  f32x4 pv;
  #pragma unroll
  for (int j = 0; j < 4; j++) pv[j] = __bfloat162float(pld.h[j]);
  #pragma unroll
  for (int k = 0; k < 2; k++){
    const __hip_bfloat16* Sr = S + ((long long)((k*8 + b)*NTOK) + i) * NTOK;
    union { uint2 u; __hip_bfloat16 h[4]; } ld;
    ld.u = *(const uint2*)&Sr[c0];
    f32x4 v;
    #pragma unroll
    for (int j = 0; j < 4; j++) v[j] = __bfloat162float(ld.h[j]);
    float mx = fmaxf(fmaxf(v[0], v[1]), fmaxf(v[2], v[3]));
    mx = blockMax(mx, red);
    float s = 0.f;
    #pragma unroll
    for (int j = 0; j < 4; j++){ v[j] = __expf(v[j] - mx); s += v[j]; }
    s = blockSum(s, red);
    float inv = 1.f / s;
    float e = 0.f;
    float* arow = k ? a1 : a0;
    f32x4 at;
    #pragma unroll
    for (int j = 0; j < 4; j++){
      at[j] = (1.f - g) * (v[j] * inv) + g * pv[j];
      e += -at[j] * __logf(at[j] + 1e-8f);
    }
    *(f32x4*)&arow[c0] = at;
    ent[k] = blockSum(e, red);
  }
  float h0 = 2.f - 2.f / (1.f + __expf(-ht * ent[0]));
  float h1 = 2.f - 2.f / (1.f + __expf(-ht * ent[1]));
  bool fg = (h0 >= h1);
  if (tid == 0) heat[row] = fg ? h0 : h1;
  const float* sel = fg ? a0 : a1;
  f32x4 sv = *(const f32x4*)&sel[c0];
  union { __hip_bfloat16 h[4]; uint2 u; } pk;
  #pragma unroll
  for (int j = 0; j < 4; j++) pk.h[j] = __float2bfloat16(sv[j]);
  *(uint2*)(attnc + ((long long)b*NTOK + i)*NTOK + c0) = pk.u;
}

// ---------------- x,y -> xy bf16 (B,1025,1536) ----------------
__global__ __launch_bounds__(256) void conv_xy_kernel(
    const float* __restrict__ x, const float* __restrict__ y, __hip_bfloat16* __restrict__ xy)
{
  long long idx = (long long)blockIdx.x*256 + threadIdx.x;   // < B*1025*768
  int d = (int)(idx % DIM);
  long long br = idx / DIM;     // b*1025 + r
  int r = (int)(br % NP1);
  xy[br*1536 + d] = __float2bfloat16(x[idx]);
  if (r == 0) xy[br*1536 + DIM + d] = __float2bfloat16(y[idx]);
}

// in fp32 [R][C] -> outT bf16 [C][R]; optional straight outS bf16 [R][C];
// optional scaled transposes outT1/outT2 (|sc1[r]|,|sc2[r]| along original row r)
__global__ __launch_bounds__(256) void transpose_conv_kernel(
    const float* __restrict__ in, long long sIn, int ldin,
    __hip_bfloat16* __restrict__ outT, long long sT,
    __hip_bfloat16* __restrict__ outS, long long sS,
    int R, int C,
    const float* __restrict__ sc1, const float* __restrict__ sc2,
    __hip_bfloat16* __restrict__ outT1, __hip_bfloat16* __restrict__ outT2)
{
  __shared__ float tile[32][33];
  int bx = blockIdx.x, by = blockIdx.y, z = blockIdx.z;
  const float* inb = in + (long long)z*sIn;
  int tx = threadIdx.x & 31, ty = threadIdx.x >> 5;
  #pragma unroll
  for (int p = 0; p < 4; p++){
    int r = by*32 + p*8 + ty;
    int c = bx*32 + tx;
    float v = inb[(long long)r*ldin + c];
    tile[p*8 + ty][tx] = v;
    if (outS) outS[(long long)z*sS + (long long)r*C + c] = __float2bfloat16(v);
  }
  __syncthreads();
  #pragma unroll
  for (int p = 0; p < 4; p++){
    int c = bx*32 + p*8 + ty;   // original col
    int r = by*32 + tx;         // original row
    float v = tile[tx][p*8 + ty];
    long long oidx = (long long)z*sT + (long long)c*R + r;
    outT[oidx] = __float2bfloat16(v);
    if (outT1) outT1[(long long)c*R + r] = __float2bfloat16(v * fabsf(sc1[r]));
    if (outT2) outT2[(long long)c*R + r] = __float2bfloat16(v * fabsf(sc2[r]));
  }
}

// ---------------- bf16 MFMA GEMM (32x32x16, BK=64), BT form, templated tile ----------------
// MT = m-subtiles(32) per wave: block tile = (MT*64) x 128, wave tile = (MT*32) x 64.
// MT=2: 128x128 (the round-5 sweet spot). MT=1: 64x128 (deep grids for tail-bound shapes).
// C[z][M][N] = alpha * A[(z&maskA)][M][K] * B[(z>>shiftB)&maskB][N][K]^T  (+ epilogue)
// EPI: 1 = bf16 alpha*acc ; 2 = bf16 gelu(acc+bias) ; 3 = fp32 xres + heatrow*(acc+bias) flat rows
// LDS rows are 64 bf16 (128B = full 32-bank span; conflict-clean); 16B chunks XOR-swizzled
// by (row&7). K % 64 == 0. Single-buffered: dbuf regressed (r7: BK=32 rows tripled conflicts;
// m99/m100/m131-141: no win on this structure).
__device__ __forceinline__ void async16(const __bf16* gp, __bf16* lp){
  __builtin_amdgcn_global_load_lds(
      (const __attribute__((address_space(1))) void*)gp,
      (__attribute__((address_space(3))) void*)lp, 16, 0, 0);
}

template<int MT, int EPI>
__global__ __launch_bounds__(256) void mfma_gemm(
    const __bf16* __restrict__ A, const __bf16* __restrict__ Bm, void* __restrict__ Cv,
    int M, int N, int K, int lda, int ldb, int ldc,
    long long sAz, long long sBz, long long sCz,
    int maskA, int shiftB, int maskB, float alpha,
    const float* __restrict__ bias,
    const float* __restrict__ xres,
    const float* __restrict__ heat)
{
  __shared__ __align__(16) __bf16 Atile[MT*64*64];
  __shared__ __align__(16) __bf16 Btile[128*64];

  const int tid  = threadIdx.x;
  const int lane = tid & 63;
  const int wv   = tid >> 6;
  const int wr   = wv >> 1, wc = wv & 1;
  const int n0 = blockIdx.x * 128, m0 = blockIdx.y * (MT*64);
  const int z  = blockIdx.z;

  const __bf16* Ab = A  + (long long)(z & maskA) * sAz;
  const __bf16* Bb = Bm + (long long)((z >> shiftB) & maskB) * sBz;

  // ---- staging: per-lane global pointers (loop-carried), swizzled source chunk ----
  const __bf16* gA[2*MT]; __bf16* lA[2*MT];
  #pragma unroll
  for (int i = 0; i < 2*MT; i++){
    int s0  = i*256 + wv*64;
    int s   = s0 + lane;
    int row = s >> 3;
    int kc  = (s & 7) ^ (row & 7);
    int gm = m0 + row; if (gm > M-1) gm = M-1;
    gA[i] = Ab + (long long)gm * lda + kc * 8;
    lA[i] = &Atile[s0 * 8];
  }
  const __bf16* gB[4]; __bf16* lB[4];
  #pragma unroll
  for (int i = 0; i < 4; i++){
    int s0  = i*256 + wv*64;
    int s   = s0 + lane;
    int row = s >> 3;
    int kc  = (s & 7) ^ (row & 7);
    int gn = n0 + row; if (gn > N-1) gn = N-1;
    gB[i] = Bb + (long long)gn * ldb + kc * 8;
    lB[i] = &Btile[s0 * 8];
  }

  // ---- fragment read pointers (precomputed, swizzled) ----
  const int fm = lane & 31;        // row within 32-subtile
  const int kq = lane >> 5;        // 8-elem half of each K=16 step
  const __bf16* pA[MT][4]; const __bf16* pB[2][4];
  #pragma unroll
  for (int rr = 0; rr < MT; rr++){
    int rowA = wr*(MT*32) + rr*32 + fm;
    #pragma unroll
    for (int st = 0; st < 4; st++)
      pA[rr][st] = &Atile[rowA*64 + ((st*2 + kq) ^ (rowA & 7)) * 8];
  }
  #pragma unroll
  for (int cc = 0; cc < 2; cc++){
    int rowB = wc*64 + cc*32 + fm;
    #pragma unroll
    for (int st = 0; st < 4; st++)
      pB[cc][st] = &Btile[rowB*64 + ((st*2 + kq) ^ (rowB & 7)) * 8];
  }

  f32x16 acc[MT][2] = {};

  for (int k0 = 0; k0 < K; k0 += 64){
    __syncthreads();
    #pragma unroll
    for (int i = 0; i < 2*MT; i++) async16(gA[i], lA[i]);
    #pragma unroll
    for (int i = 0; i < 4; i++)    async16(gB[i], lB[i]);
    #pragma unroll
    for (int i = 0; i < 2*MT; i++) gA[i] += 64;
    #pragma unroll
    for (int i = 0; i < 4; i++)    gB[i] += 64;
    __syncthreads();
    #pragma unroll
    for (int st = 0; st < 4; st++){
      bf16x8 b0 = *(const bf16x8*)pB[0][st];
      bf16x8 b1 = *(const bf16x8*)pB[1][st];
      #pragma unroll
      for (int rr = 0; rr < MT; rr++){
        bf16x8 a = *(const bf16x8*)pA[rr][st];
        acc[rr][0] = __builtin_amdgcn_mfma_f32_32x32x16_bf16(a, b0, acc[rr][0], 0, 0, 0);
        acc[rr][1] = __builtin_amdgcn_mfma_f32_32x32x16_bf16(a, b1, acc[rr][1], 0, 0, 0);
      }
    }
  }

  // ---- epilogue: C/D layout col=lane&31, row=(reg&3)+8*(reg>>2)+4*(lane>>5) ----
  const int col_l = lane & 31;
  const int row_q = (lane >> 5) * 4;
  #pragma unroll
  for (int rr = 0; rr < MT; rr++){
    #pragma unroll
    for (int cc = 0; cc < 2; cc++){
      int gn  = n0 + wc*64 + cc*32 + col_l;
      if (gn >= N) continue;
      int gmb = m0 + wr*(MT*32) + rr*32 + row_q;
      f32x16 v = acc[rr][cc];
      #pragma unroll
      for (int g = 0; g < 4; g++){
        #pragma unroll
        for (int q = 0; q < 4; q++){
          int gm = gmb + g*8 + q;
          if (gm >= M) continue;
          float cval = alpha * v[g*4 + q];
          long long cidx = (long long)z*sCz + (long long)gm*ldc + gn;
          if (EPI == 1){
            ((__hip_bfloat16*)Cv)[cidx] = __float2bfloat16(cval);
          } else if (EPI == 2){
            float h = cval + bias[gn];
            // tanh-form gelu (max |err| vs exact ~3e-3; validated r6/r7, absmax unchanged)
            float u = 0.7978845608f * (h + 0.044715f * h * h * h);
            float tt = 1.f - 2.f / (__expf(2.f * u) + 1.f);
            float ge = 0.5f * h * (1.f + tt);
            ((__hip_bfloat16*)Cv)[cidx] = __float2bfloat16(ge);
          } else {
            float h = cval + bias[gn];
            int bq = gm / NP1;
            int rr2 = gm - bq * NP1;
            float f = (rr2 == 0) ? 1.f : heat[bq*NTOK + (rr2 - 1)];
            ((float*)Cv)[cidx] = xres[cidx] + f * h;
          }
        }
      }
    }
  }
}

extern "C" void kernel_launch(void* const* d_in, const int* in_sizes, int n_in,
                              void* d_out, int out_size, void* d_ws, size_t ws_size,
                              hipStream_t stream)
{
  const float* x       = (const float*)d_in[0];
  const float* y       = (const float*)d_in[1];
  const float* coords  = (const float*)d_in[2];
  const float* U       = (const float*)d_in[3];
  const float* S1      = (const float*)d_in[4];
  const float* S2      = (const float*)d_in[5];
  const float* gating  = (const float*)d_in[6];
  const float* h_temp  = (const float*)d_in[7];
  const float* p_temp  = (const float*)d_in[8];
  const float* pos_emb = (const float*)d_in[9];
  const float* W1      = (const float*)d_in[10];
  const float* b1      = (const float*)d_in[11];
  const float* W2      = (const float*)d_in[12];
  const float* b2      = (const float*)d_in[13];
  float* out = (float*)d_out;
  char* ws = (char*)d_ws;

  size_t off = 0;
  auto alloc = [&](size_t bytes){ size_t r = off; off = (off + bytes + 255) & ~(size_t)255; return r; };
  const long long NN  = (long long)NTOK * NTOK;
  const long long DD  = (long long)DIM * DIM;
  const size_t o_pos  = alloc(NN * 2);                       // pos bf16
  const size_t o_S    = alloc((size_t)BB*NP1*DFF * 2);       // hg bf16 region; S bf16 (32MB) overlays start
  const size_t o_xy   = alloc((size_t)BB*NP1*1536 * 2);      // xy bf16
  const size_t o_yb   = alloc((size_t)BB*NTOK*DIM * 2);      // yb bf16
  const size_t o_ybT  = alloc((size_t)BB*DIM*NTOK * 2);      // ybT bf16
  const size_t o_xs   = alloc((size_t)2*BB*NTOK*DIM * 2);    // xs bf16 (k,b,N,D)
  const size_t o_attn = alloc((size_t)BB*NN * 2);            // attnc bf16
  const size_t o_UT   = alloc((size_t)DD * 2);
  const size_t o_UTs  = alloc((size_t)2*DD * 2);             // UTs1,UTs2
  const size_t o_Mk   = alloc((size_t)2*DD * 2);             // M1,M2 bf16
  const size_t o_W1T  = alloc((size_t)DFF*2*DIM * 2);
  const size_t o_W2T  = alloc((size_t)DIM*DFF * 2);
  const size_t o_heat = alloc((size_t)BB*NTOK * 4);

  __hip_bfloat16* S_bf = (__hip_bfloat16*)(ws + o_S);        // (2,B,N,N) bf16
  __hip_bfloat16* hg   = (__hip_bfloat16*)(ws + o_S);        // overlay (post-rowproc)
  __hip_bfloat16* xy   = (__hip_bfloat16*)(ws + o_xy);
  __hip_bfloat16* yb   = (__hip_bfloat16*)(ws + o_yb);
  __hip_bfloat16* ybT  = (__hip_bfloat16*)(ws + o_ybT);
  __hip_bfloat16* xs   = (__hip_bfloat16*)(ws + o_xs);
  __hip_bfloat16* attnc= (__hip_bfloat16*)(ws + o_attn);
  __hip_bfloat16* UT   = (__hip_bfloat16*)(ws + o_UT);
  __hip_bfloat16* UTs  = (__hip_bfloat16*)(ws + o_UTs);
  __hip_bfloat16* Mk   = (__hip_bfloat16*)(ws + o_Mk);
  __hip_bfloat16* W1T  = (__hip_bfloat16*)(ws + o_W1T);
  __hip_bfloat16* W2T  = (__hip_bfloat16*)(ws + o_W2T);
  __hip_bfloat16* pos  = (__hip_bfloat16*)(ws + o_pos);
  float* heat = (float*)(ws + o_heat);

  const float scale = 0.03608439182435161f; // 768^-0.5
  dim3 blk(256);

  // ---- prep ----
  pos_kernel<<<dim3(NTOK), blk, 0, stream>>>(coords, pos_emb, p_temp, pos);
  conv_xy_kernel<<<dim3((BB*NP1*DIM)/256), blk, 0, stream>>>(x, y, xy);
  transpose_conv_kernel<<<dim3(DIM/32, DIM/32, 1), blk, 0, stream>>>(
      U, 0LL, DIM, UT, 0LL, nullptr, 0LL, DIM, DIM, S1, S2, UTs, UTs + DD);
  transpose_conv_kernel<<<dim3(DFF/32, (2*DIM)/32, 1), blk, 0, stream>>>(
      W1, 0LL, DFF, W1T, 0LL, nullptr, 0LL, 2*DIM, DFF, nullptr, nullptr, nullptr, nullptr);
  transpose_conv_kernel<<<dim3(DIM/32, DFF/32, 1), blk, 0, stream>>>(
      W2, 0LL, DIM, W2T, 0LL, nullptr, 0LL, DFF, DIM, nullptr, nullptr, nullptr, nullptr);
  transpose_conv_kernel<<<dim3(DIM/32, NTOK/32, BB), blk, 0, stream>>>(
      y + DIM, (long long)NP1*DIM, DIM, ybT, (long long)DIM*NTOK, yb, (long long)NTOK*DIM,
      NTOK, DIM, nullptr, nullptr, nullptr, nullptr);

  // ---- G1: M_k = UT @ UTs_k^T (symmetric), z=2 ----
  mfma_gemm<2,1><<<dim3(DIM/128, DIM/128, 2), blk, 0, stream>>>(
      (const __bf16*)UT, (const __bf16*)UTs, Mk,
      DIM, DIM, DIM, DIM, DIM, DIM,
      0LL, DD, DD, 0, 0, 1, 1.f, nullptr, nullptr, nullptr);

  // ---- G2: xs[k,b] = xb[b] @ M_k^T, z=k*8+b ----
  mfma_gemm<2,1><<<dim3(DIM/128, NTOK/128, 16), blk, 0, stream>>>(
      (const __bf16*)(xy + 1536), (const __bf16*)Mk, xs,
      NTOK, DIM, DIM, 1536, DIM, DIM,
      (long long)NP1*1536, DD, (long long)NTOK*DIM,
      7, 3, 1, 1.f, nullptr, nullptr, nullptr);

  // ---- G3: S[k,b] = bf16( scale * xs[k,b] @ yb[b]^T ) ----
  mfma_gemm<2,1><<<dim3(NTOK/128, NTOK/128, 16), blk, 0, stream>>>(
      (const __bf16*)xs, (const __bf16*)yb, S_bf,
      NTOK, NTOK, DIM, DIM, DIM, NTOK,
      (long long)NTOK*DIM, (long long)NTOK*DIM, NN,
      15, 0, 7, scale, nullptr, nullptr, nullptr);

  // ---- rowproc: softmax + mix + entropy + select ----
  rowproc_kernel<<<dim3(BB*NTOK), blk, 0, stream>>>(S_bf, pos, attnc, heat, gating, h_temp);

  // ---- G4: y_out[b] = attnc[b] @ ybT[b]^T -> xy cols 768.., rows 1.. ---- (MT=1: 768 blocks, 3/CU)
  mfma_gemm<1,1><<<dim3(DIM/128, NTOK/64, BB), blk, 0, stream>>>(
      (const __bf16*)attnc, (const __bf16*)ybT, xy + 1536 + DIM,
      NTOK, DIM, NTOK, NTOK, NTOK, 1536,
      NN, (long long)DIM*NTOK, (long long)NP1*1536,
      7, 0, 7, 1.f, nullptr, nullptr, nullptr);

  // ---- G5: hg = gelu(xy @ W1T^T + b1), flattened M=8200 ---- (MT=2: 1560 blocks)
  mfma_gemm<2,2><<<dim3(DFF/128, (BB*NP1 + 127)/128, 1), blk, 0, stream>>>(
      (const __bf16*)xy, (const __bf16*)W1T, hg,
      BB*NP1, DFF, 2*DIM, 1536, 1536, DFF,
      0LL, 0LL, 0LL, 0, 0, 0, 1.f, b1, nullptr, nullptr);

  // ---- G6: out = x + heatrow*(hg @ W2T^T + b2), flattened M=8200 ---- (MT=1: 774 blocks, 3/CU)
  mfma_gemm<1,3><<<dim3(DIM/128, (BB*NP1 + 63)/64, 1), blk, 0, stream>>>(
      (const __bf16*)hg, (const __bf16*)W2T, out,
      BB*NP1, DIM, DFF, DFF, DFF, DIM,
      0LL, 0LL, 0LL, 0, 0, 0, 1.f, b2, x, heat);
}